// Round 9
// baseline (112.316 us; speedup 1.0000x reference)
//
#include <hip/hip_runtime.h>
#include <hip/hip_bf16.h>
#include <cstdint>

// Problem constants: B=1024, S=8, H=16, DK=DV=32, D=512
#define NB 1024
#define ND 512
#define NM 8192  // B*S rows

typedef __attribute__((ext_vector_type(8))) short short8;
typedef __attribute__((ext_vector_type(8))) __bf16 bf16x8;
typedef __attribute__((ext_vector_type(4))) float f32x4;
typedef __attribute__((ext_vector_type(4))) unsigned short ushort4v;

__device__ __forceinline__ unsigned short f2bf(float f) {
  uint32_t x = __builtin_bit_cast(uint32_t, f);
  x += 0x7fffu + ((x >> 16) & 1u);  // RNE
  return (unsigned short)(x >> 16);
}
__device__ __forceinline__ float bf2f(unsigned short u) {
  return __builtin_bit_cast(float, (uint32_t)u << 16);
}
__device__ __forceinline__ f32x4 mfma16(short8 a, short8 b, f32x4 c) {
  return __builtin_amdgcn_mfma_f32_16x16x32_bf16(
      __builtin_bit_cast(bf16x8, a), __builtin_bit_cast(bf16x8, b), c, 0, 0, 0);
}
__device__ __forceinline__ void gl_lds16(const unsigned short* g, unsigned short* lds) {
  __builtin_amdgcn_global_load_lds(
      (const __attribute__((address_space(1))) unsigned int*)g,
      (__attribute__((address_space(3))) unsigned int*)lds, 16, 0, 0);
}
__device__ __forceinline__ short8 cvt8(float4 a, float4 b) {
  short8 r;
  r[0] = (short)f2bf(a.x); r[1] = (short)f2bf(a.y);
  r[2] = (short)f2bf(a.z); r[3] = (short)f2bf(a.w);
  r[4] = (short)f2bf(b.x); r[5] = (short)f2bf(b.y);
  r[6] = (short)f2bf(b.z); r[7] = (short)f2bf(b.w);
  return r;
}
#define VMCNT0() asm volatile("s_waitcnt vmcnt(0)" ::: "memory")
#define VMCNT4() asm volatile("s_waitcnt vmcnt(4)" ::: "memory")
#define LGKMCNT0() asm volatile("s_waitcnt lgkmcnt(0)" ::: "memory")
#define BAR() __builtin_amdgcn_s_barrier()

// ---- fp32 -> bf16 pre-convert: weights only (4 x 262144)
__global__ __launch_bounds__(256) void convert_w(
    const float* __restrict__ Wq, const float* __restrict__ Wk,
    const float* __restrict__ Wv, const float* __restrict__ Wo,
    unsigned short* __restrict__ Wqb, unsigned short* __restrict__ Wkb,
    unsigned short* __restrict__ Wvb, unsigned short* __restrict__ Wob) {
  const int idx = blockIdx.x * 256 + threadIdx.x;
  const int sel = idx >> 15, o = (idx & 32767) * 8;
  const float* src = sel == 0 ? Wq : sel == 1 ? Wk : sel == 2 ? Wv : Wo;
  unsigned short* dst = sel == 0 ? Wqb : sel == 1 ? Wkb : sel == 2 ? Wvb : Wob;
  const float4 a = ((const float4*)(src + o))[0];
  const float4 b = ((const float4*)(src + o))[1];
  *(short8*)(dst + o) = cvt8(a, b);
}

// ---- Fully fused: QKV-proj -> masked softmax attention (+hyper gate) ->
// Wo-proj + bias + residual -> LayerNorm.  One block = 4 batches (32 rows),
// 512 threads = 8 waves; wave w owns output cols [w*64, w*64+64) = heads
// {2w, 2w+1}.  Weights stream L2->LDS tiles (BK=32, dbuf, counted vmcnt).
// LDS exactly 160KB: Wt dbuf 64KB + q 32KB + k 32KB + v 32KB; ctx overwrites
// q in-place; LN scratch reuses k.
__global__ __launch_bounds__(512, 2) void fused_kernel(
    const float* __restrict__ Qf, const float* __restrict__ Kf,
    const float* __restrict__ Vf, const int* __restrict__ mask,
    const float* __restrict__ hyper,
    const unsigned short* __restrict__ Wqb, const unsigned short* __restrict__ Wkb,
    const unsigned short* __restrict__ Wvb, const unsigned short* __restrict__ Wob,
    const float* __restrict__ bq, const float* __restrict__ bk,
    const float* __restrict__ bv, const float* __restrict__ bo,
    const float* __restrict__ lg, const float* __restrict__ lb,
    float* __restrict__ out, float* __restrict__ wout) {
  __shared__ unsigned short Wt0[512 * 32];  // 32KB W-tile buf 0
  __shared__ unsigned short Wt1[512 * 32];  // 32KB W-tile buf 1
  __shared__ unsigned short qs[32 * 512];   // q (becomes ctx in-place)
  __shared__ unsigned short ks[32 * 512];   // k (becomes LN scratch)
  __shared__ unsigned short vs[32 * 512];   // v

  const int tid = threadIdx.x;
  const int lane = tid & 63, wid = tid >> 6;
  const int l15 = lane & 15, l4 = lane >> 4;
  const int b0 = blockIdx.x;
  const int mBase = b0 * 32;

  f32x4 acc[2][4] = {};

  // ---- W tile staging: [512 n][32 k] bf16, row-pair (128B = 8 granule)
  // XOR swizzle, pre-applied on the GLOBAL source (rule #21); LDS dest linear.
  auto stageW = [&](const unsigned short* W, int ktl, unsigned short* wt) {
#pragma unroll
    for (int i = 0; i < 4; ++i) {
      const int rp = wid * 32 + i * 8 + (lane >> 3);       // abs row-pair
      const int gl = (lane & 7) ^ (rp & 7);                // logical granule
      const int rsrc = rp * 2 + (gl >> 2);                 // W row
      const int cel = ktl * 32 + (gl & 3) * 8;             // W col (elem)
      gl_lds16(W + (size_t)rsrc * 512 + cel, wt + (wid * 64 + i * 16) * 32);
    }
  };
  // B-frag read: row n, granule l4; 2-way bank alias (free).
  auto computeG = [&](const unsigned short* wt, short8 a0, short8 a1) {
    short8 bfr[4];
#pragma unroll
    for (int nf = 0; nf < 4; ++nf) {
      const int n = wid * 64 + nf * 16 + l15;
      const int rp = n >> 1;
      const int gp = ((n & 1) * 4 + l4) ^ (rp & 7);
      bfr[nf] = *(const short8*)((const char*)wt + rp * 128 + gp * 16);
    }
#pragma unroll
    for (int nf = 0; nf < 4; ++nf) {
      acc[0][nf] = mfma16(a0, bfr[nf], acc[0][nf]);
      acc[1][nf] = mfma16(a1, bfr[nf], acc[1][nf]);
    }
  };
  // A-frags direct from global f32 (L1-shared across waves), 2-deep pipeline.
  auto issueA = [&](int ktg, float4 (&d)[4]) {
    if (ktg >= 48) return;
    const float* Am = ktg < 16 ? Qf : (ktg < 32 ? Kf : Vf);
    const int ktl = ktg & 15;
#pragma unroll
    for (int m = 0; m < 2; ++m) {
      const float* p = Am + (size_t)(mBase + m * 16 + l15) * 512 + ktl * 32 + l4 * 8;
      d[m * 2] = ((const float4*)p)[0];
      d[m * 2 + 1] = ((const float4*)p)[1];
    }
  };
  // q/k/v LDS: [32 r][512 c] bf16, granule (16B) swizzle g' = g ^ (row&7).
  auto epiQKV = [&](unsigned short* dst, const float* bias) {
#pragma unroll
    for (int nf = 0; nf < 4; ++nf) {
      const int col = wid * 64 + nf * 16 + l15;
      const float bb = bias[col];
      const int g = col >> 3;
      const int eb = (col & 7) * 2;
#pragma unroll
      for (int m = 0; m < 2; ++m)
#pragma unroll
        for (int r = 0; r < 4; ++r) {
          const int row = m * 16 + l4 * 4 + r;
          *(unsigned short*)((char*)dst + row * 1024 + ((g ^ (row & 7)) * 16) + eb) =
              f2bf(acc[m][nf][r] + bb);
          acc[m][nf][r] = 0.f;
        }
    }
  };

  // ================= GEMM1-3: 48 continuous K-tiles =================
  float4 aP0[4], aP1[4];
  short8 afr0, afr1;
  stageW(Wqb, 0, Wt0);
  issueA(0, aP0);
  issueA(1, aP1);
  VMCNT0();
  afr0 = cvt8(aP0[0], aP0[1]);
  afr1 = cvt8(aP0[2], aP0[3]);
  BAR();
  for (int kt2 = 0; kt2 < 48; kt2 += 2) {
    const int kB = kt2 + 1;
    const unsigned short* WB = kB < 16 ? Wqb : (kB < 32 ? Wkb : Wvb);
    // even ktile kt2: compute Wt0
    if (kB < 48) stageW(WB, kB & 15, Wt1);
    issueA(kt2 + 2, aP0);
    computeG(Wt0, afr0, afr1);
    VMCNT4();  // A(kt2+1)+W(kt2+1) done; A(kt2+2) stays in flight
    afr0 = cvt8(aP1[0], aP1[1]);
    afr1 = cvt8(aP1[2], aP1[3]);
    BAR();
    // odd ktile kB: compute Wt1
    if (kB + 1 < 48) {
      const unsigned short* WC = (kB + 1) < 16 ? Wqb : ((kB + 1) < 32 ? Wkb : Wvb);
      stageW(WC, (kB + 1) & 15, Wt0);
    }
    issueA(kB + 2, aP1);
    if (kt2 == 46) VMCNT0();  // tail: W(47) must land (no A-issues to count)
    computeG(Wt1, afr0, afr1);
    if (kB == 15) epiQKV(qs, bq);
    else if (kB == 31) epiQKV(ks, bk);
    else if (kB == 47) epiQKV(vs, bv);
    VMCNT4();
    afr0 = cvt8(aP0[0], aP0[1]);
    afr1 = cvt8(aP0[2], aP0[3]);
    BAR();
  }

  // ================= attention (wave-local heads 2w, 2w+1) =================
  const int ai = lane >> 3, aj = lane & 7;
  for (int p = 0; p < 8; ++p) {
    const int bb = p >> 1, hh = p & 1;
    const int h = wid * 2 + hh;
    const int b = b0 * 4 + bb;
    const int qrow = bb * 8 + ai, krow = bb * 8 + aj;
    float dot = 0.f;
#pragma unroll
    for (int c = 0; c < 4; ++c) {
      const short8 qv = *(const short8*)((const char*)qs + qrow * 1024 +
                                         (((h * 4 + c) ^ (qrow & 7)) * 16));
      const short8 kv = *(const short8*)((const char*)ks + krow * 1024 +
                                         (((h * 4 + c) ^ (krow & 7)) * 16));
#pragma unroll
      for (int e = 0; e < 8; ++e)
        dot += bf2f((unsigned short)qv[e]) * bf2f((unsigned short)kv[e]);
    }
    float score = dot * 0.17677669529663687f;  // 1/sqrt(32)
    if (mask[b * 64 + ai * 8 + aj]) score = -1e9f;
    float mx = score;
#pragma unroll
    for (int o = 4; o; o >>= 1) mx = fmaxf(mx, __shfl_xor(mx, o, 8));
    const float e = __expf(score - mx);
    float sm = e;
#pragma unroll
    for (int o = 4; o; o >>= 1) sm += __shfl_xor(sm, o, 8);
    const float w = e / sm;
    wout[(size_t)(b * 16 + h) * 64 + lane] = w;
    // PV: lane covers (i=ai, d0=(lane&7)*4); v row-swizzled b64 reads
    const int d0 = (lane & 7) * 4;
    const int gv = h * 4 + ((lane & 7) >> 1);
    const int ob = (lane & 1) * 8;
    float c0 = 0, c1 = 0, c2 = 0, c3 = 0;
#pragma unroll
    for (int jj = 0; jj < 8; ++jj) {
      const float wj = __shfl(w, jj, 8);
      const int vrow = bb * 8 + jj;
      const ushort4v vv = *(const ushort4v*)((const char*)vs + vrow * 1024 +
                                             ((gv ^ (vrow & 7)) * 16) + ob);
      c0 += wj * bf2f(vv[0]); c1 += wj * bf2f(vv[1]);
      c2 += wj * bf2f(vv[2]); c3 += wj * bf2f(vv[3]);
    }
    const float4 hv = *(const float4*)(hyper + (size_t)b * 4096 + h * 256 + ai * 32 + d0);
    ushort4v co;
    co[0] = f2bf(c0 * hv.x); co[1] = f2bf(c1 * hv.y);
    co[2] = f2bf(c2 * hv.z); co[3] = f2bf(c3 * hv.w);
    // ctx overwrites q in-place (same wave already consumed q for this pair)
    *(ushort4v*)((char*)qs + qrow * 1024 + ((gv ^ (qrow & 7)) * 16) + ob) = co;
  }

  // ================= GEMM4: out = ctx @ Wo^T =================
  auto ldCtx = [&](int kt, short8& a0, short8& a1) {
#pragma unroll
    for (int m = 0; m < 2; ++m) {
      const int row = m * 16 + l15;
      const int g = kt * 4 + l4;
      const short8 v = *(const short8*)((const char*)qs + row * 1024 +
                                        ((g ^ (row & 7)) * 16));
      if (m == 0) a0 = v; else a1 = v;
    }
  };
  stageW(Wob, 0, Wt0);
  LGKMCNT0();  // ctx ds_writes visible across waves
  VMCNT0();
  BAR();
  for (int kt = 0; kt < 16; kt += 2) {
    if (kt + 1 < 16) stageW(Wob, kt + 1, Wt1);
    ldCtx(kt, afr0, afr1);
    computeG(Wt0, afr0, afr1);
    VMCNT0();
    BAR();
    if (kt + 2 < 16) stageW(Wob, kt + 2, Wt0);
    ldCtx(kt + 1, afr0, afr1);
    computeG(Wt1, afr0, afr1);
    VMCNT0();
    BAR();
  }

  // ================= epilogue: +bo +resid(Q), LayerNorm, store ============
  float bov[4], lgv[4], lbv[4];
#pragma unroll
  for (int nf = 0; nf < 4; ++nf) {
    const int col = wid * 64 + nf * 16 + l15;
    bov[nf] = bo[col]; lgv[nf] = lg[col]; lbv[nf] = lb[col];
  }
  float ps[8], ps2[8];
#pragma unroll
  for (int m = 0; m < 2; ++m)
#pragma unroll
    for (int r = 0; r < 4; ++r) {
      const int row = m * 16 + l4 * 4 + r;
      float s = 0.f, s2 = 0.f;
#pragma unroll
      for (int nf = 0; nf < 4; ++nf) {
        const int col = wid * 64 + nf * 16 + l15;
        float v = acc[m][nf][r] + bov[nf] + Qf[(size_t)(mBase + row) * 512 + col];
        acc[m][nf][r] = v;
        s += v; s2 += v * v;
      }
      ps[m * 4 + r] = s; ps2[m * 4 + r] = s2;
    }
#pragma unroll
  for (int idx = 0; idx < 8; ++idx)
#pragma unroll
    for (int o = 1; o < 16; o <<= 1) {
      ps[idx] += __shfl_xor(ps[idx], o, 64);
      ps2[idx] += __shfl_xor(ps2[idx], o, 64);
    }
  float* scr = (float*)ks;   // k dead; 2KB scratch
  float* scr2 = scr + 256;
  if (l15 == 0) {
#pragma unroll
    for (int m = 0; m < 2; ++m)
#pragma unroll
      for (int r = 0; r < 4; ++r) {
        const int row = m * 16 + l4 * 4 + r;
        scr[row * 8 + wid] = ps[m * 4 + r];
        scr2[row * 8 + wid] = ps2[m * 4 + r];
      }
  }
  LGKMCNT0();
  BAR();
#pragma unroll
  for (int m = 0; m < 2; ++m)
#pragma unroll
    for (int r = 0; r < 4; ++r) {
      const int row = m * 16 + l4 * 4 + r;
      float s = 0.f, s2 = 0.f;
#pragma unroll
      for (int wv = 0; wv < 8; ++wv) {
        s += scr[row * 8 + wv];
        s2 += scr2[row * 8 + wv];
      }
      const float mu = s * (1.f / 512.f);
      const float inv = rsqrtf(s2 * (1.f / 512.f) - mu * mu + 1e-5f);
#pragma unroll
      for (int nf = 0; nf < 4; ++nf) {
        const int col = wid * 64 + nf * 16 + l15;
        out[(size_t)(mBase + row) * 512 + col] =
            (acc[m][nf][r] - mu) * inv * lgv[nf] + lbv[nf];
      }
    }
}

extern "C" void kernel_launch(void* const* d_in, const int* in_sizes, int n_in,
                              void* d_out, int out_size, void* d_ws, size_t ws_size,
                              hipStream_t stream) {
  const float* Q = (const float*)d_in[0];
  const float* K = (const float*)d_in[1];
  const float* V = (const float*)d_in[2];
  const int* msk = (const int*)d_in[3];
  const float* hyper = (const float*)d_in[4];
  const float* Wq = (const float*)d_in[5];
  const float* bq = (const float*)d_in[6];
  const float* Wk = (const float*)d_in[7];
  const float* bk = (const float*)d_in[8];
  const float* Wv = (const float*)d_in[9];
  const float* bv = (const float*)d_in[10];
  const float* Wo = (const float*)d_in[11];
  const float* bo = (const float*)d_in[12];
  const float* lg = (const float*)d_in[13];
  const float* lb = (const float*)d_in[14];

  float* out = (float*)d_out;           // [8192,512] fp32
  float* wout = out + (size_t)NM * ND;  // [1024,16,8,8] fp32

  unsigned short* Wqb = (unsigned short*)d_ws;
  unsigned short* Wkb = Wqb + (size_t)ND * ND;
  unsigned short* Wvb = Wkb + (size_t)ND * ND;
  unsigned short* Wob = Wvb + (size_t)ND * ND;

  convert_w<<<512, 256, 0, stream>>>(Wq, Wk, Wv, Wo, Wqb, Wkb, Wvb, Wob);
  fused_kernel<<<256, 512, 0, stream>>>(Q, K, V, msk, hyper, Wqb, Wkb, Wvb, Wob,
                                        bq, bk, bv, bo, lg, lb, out, wout);
}